// Round 3
// baseline (421.063 us; speedup 1.0000x reference)
//
#include <hip/hip_runtime.h>
#include <math.h>

typedef _Float16 f16;
typedef _Float16 f16x2 __attribute__((ext_vector_type(2)));
typedef _Float16 f16x8 __attribute__((ext_vector_type(8)));
typedef float    f32x4 __attribute__((ext_vector_type(4)));
typedef float    f32x16 __attribute__((ext_vector_type(16)));

#define NB 4096
#define LT 512
#define NC 16
#define NS 32

// workspace layout (bytes)
#define WS_P0     0                     // 32 f32, softmax(init)*256
#define WS_SIG    128                   // 32 f32, sigmoid(acc)*256
#define WS_SUMSIG 256                   // 1 f32
#define WS_FWDT   512                   // 16384 f16 = 32768 B
#define WS_BWDT   (512 + 32768)
#define WS_F      (512 + 65536)         // 32*4096 f32
#define WS_G      (WS_F + 32*4096*4)

#if __has_builtin(__builtin_amdgcn_exp2f)
#define EXP2F __builtin_amdgcn_exp2f
#else
#define EXP2F exp2f
#endif

// ---------------- prep: softmaxes + fragment-ordered fp16 transition tables ----
__global__ __launch_bounds__(512) void pdfa_prep(const float* __restrict__ tlogit,
                                                 const float* __restrict__ ilogit,
                                                 const float* __restrict__ alogit,
                                                 char* __restrict__ ws) {
    int tid = threadIdx.x;           // 512 threads = one (p,c) row each
    f16* fwdT = (f16*)(ws + WS_FWDT);
    f16* bwdT = (f16*)(ws + WS_BWDT);
    int p = tid >> 4, c = tid & 15;
    const float* row = tlogit + p * 512 + c * 32;
    float mx = row[0];
    for (int n = 1; n < 32; ++n) mx = fmaxf(mx, row[n]);
    float s = 0.f;
    for (int n = 0; n < 32; ++n) s += expf(row[n] - mx);
    float inv = 1.f / s;
    int g = p >> 3, ht = (p >> 2) & 1, d = p & 3;
    int chalf = c >> 3, j = c & 7;
    for (int n = 0; n < 32; ++n) {
        float tv = expf(row[n] - mx) * inv;
        // fwd table: GEMM D[m=n']=sum_k T[p,c,n']*y[k], A row m = lane&31 = n
        {
            int ks = 8 * g + 2 * d + chalf;
            int l = 32 * ht + n;
            fwdT[ks * 512 + l * 8 + j] = (f16)tv;
        }
        // bwd table: D[m=p]=sum_{(c,n)} T[p,c,n]*x[c]g[n], A row m = p
        {
            int g2 = n >> 3, h2 = (n >> 2) & 1, d2 = n & 3;
            int ks = 8 * g2 + 2 * d2 + chalf;
            int l = 32 * h2 + p;
            bwdT[ks * 512 + l * 8 + j] = (f16)tv;
        }
    }
    if (tid < 32) {
        float m0 = ilogit[0];
        for (int n = 1; n < 32; ++n) m0 = fmaxf(m0, ilogit[n]);
        float s0 = 0.f;
        for (int n = 0; n < 32; ++n) s0 += expf(ilogit[n] - m0);
        ((float*)(ws + WS_P0))[tid]  = 256.f * expf(ilogit[tid] - m0) / s0;
        ((float*)(ws + WS_SIG))[tid] = 256.f / (1.f + expf(-alogit[tid]));
    }
    if (tid == 0) {
        float ss = 0.f;
        for (int n = 0; n < 32; ++n) ss += 1.f / (1.f + expf(-alogit[n]));
        *(float*)(ws + WS_SUMSIG) = ss;
    }
}

// ---------------- main: 2 chains per wave (same dir, shared table), 6-way MFMA interleave
#define EC(v) ((f16)EXP2F((v) * 1.44269504089f))

#define XLOAD(XB,B0,B1,B2,B3,T) { const f32x4* sp_ = (const f32x4*)((XB) + (size_t)(T) * NC); \
    B0 = sp_[0]; B1 = sp_[1]; B2 = sp_[2]; B3 = sp_[3]; }

#define XCONV(XQ,B0,B1,B2,B3) { \
    XQ[0] = f16x2{EC(B0[0]), EC(B0[1])}; \
    XQ[1] = f16x2{EC(B0[2]), EC(B0[3])}; \
    XQ[2] = f16x2{EC(B1[0]), EC(B1[1])}; \
    XQ[3] = f16x2{EC(B1[2]), EC(B1[3])}; \
    XQ[4] = f16x2{EC(B2[0]), EC(B2[1])}; \
    XQ[5] = f16x2{EC(B2[2]), EC(B2[3])}; \
    XQ[6] = f16x2{EC(B3[0]), EC(B3[1])}; \
    XQ[7] = f16x2{EC(B3[2]), EC(B3[3])}; }

// one K-step for one chain: extract own-half state scalar, 4x v_pk_mul_f16, one MFMA
#define KCH(PPK, XQ, KS, ACC, CIN) { \
    enum { ks_ = (KS), ir_ = 2*((KS)>>3) + (((KS)>>2)&1), ch_ = ((KS)&1)*4, sel_ = ((KS)>>1)&1 }; \
    f16 pv_ = PPK[ir_][sel_]; \
    f16x2 pb_ = {pv_, pv_}; \
    f16x2 y0_ = pb_ * XQ[ch_+0], y1_ = pb_ * XQ[ch_+1], y2_ = pb_ * XQ[ch_+2], y3_ = pb_ * XQ[ch_+3]; \
    f16x8 bf_ = {y0_[0],y0_[1],y1_[0],y1_[1],y2_[0],y2_[1],y3_[0],y3_[1]}; \
    ACC = __builtin_amdgcn_mfma_f32_32x32x16_f16(af[ks_], bf_, CIN, 0, 0, 0); }

#define KA(KS, ACC, CIN) KCH(ppkA, xqA, KS, ACC, CIN)
#define KB(KS, ACC, CIN) KCH(ppkB, xqB, KS, ACC, CIN)

// both chains, 3 accs each -> same-acc dep distance = 6 MFMA slots (> ~95cyc latency)
#define STEPBODY2() { \
    f32x16 aA0, aA1, aA2, aB0, aB1, aB2; \
    KA(0,  aA0, z)   KB(0,  aB0, z)   KA(1,  aA1, z)   KB(1,  aB1, z) \
    KA(2,  aA2, z)   KB(2,  aB2, z)   KA(3,  aA0, aA0) KB(3,  aB0, aB0) \
    KA(4,  aA1, aA1) KB(4,  aB1, aB1) KA(5,  aA2, aA2) KB(5,  aB2, aB2) \
    KA(6,  aA0, aA0) KB(6,  aB0, aB0) KA(7,  aA1, aA1) KB(7,  aB1, aB1) \
    KA(8,  aA2, aA2) KB(8,  aB2, aB2) KA(9,  aA0, aA0) KB(9,  aB0, aB0) \
    KA(10, aA1, aA1) KB(10, aB1, aB1) KA(11, aA2, aA2) KB(11, aB2, aB2) \
    KA(12, aA0, aA0) KB(12, aB0, aB0) KA(13, aA1, aA1) KB(13, aB1, aB1) \
    KA(14, aA2, aA2) KB(14, aB2, aB2) KA(15, aA0, aA0) KB(15, aB0, aB0) \
    KA(16, aA1, aA1) KB(16, aB1, aB1) KA(17, aA2, aA2) KB(17, aB2, aB2) \
    KA(18, aA0, aA0) KB(18, aB0, aB0) KA(19, aA1, aA1) KB(19, aB1, aB1) \
    KA(20, aA2, aA2) KB(20, aB2, aB2) KA(21, aA0, aA0) KB(21, aB0, aB0) \
    KA(22, aA1, aA1) KB(22, aB1, aB1) KA(23, aA2, aA2) KB(23, aB2, aB2) \
    KA(24, aA0, aA0) KB(24, aB0, aB0) KA(25, aA1, aA1) KB(25, aB1, aB1) \
    KA(26, aA2, aA2) KB(26, aB2, aB2) KA(27, aA0, aA0) KB(27, aB0, aB0) \
    KA(28, aA1, aA1) KB(28, aB1, aB1) KA(29, aA2, aA2) KB(29, aB2, aB2) \
    KA(30, aA0, aA0) KB(30, aB0, aB0) KA(31, aA1, aA1) KB(31, aB1, aB1) \
    pfinA = aA0 + aA1; pfinB = aB0 + aB1; \
    pfinA = pfinA + aA2; pfinB = pfinB + aB2; \
    ppkA[0] = f16x2{(f16)pfinA[0],  (f16)pfinA[1]}; \
    ppkA[1] = f16x2{(f16)pfinA[2],  (f16)pfinA[3]}; \
    ppkA[2] = f16x2{(f16)pfinA[4],  (f16)pfinA[5]}; \
    ppkA[3] = f16x2{(f16)pfinA[6],  (f16)pfinA[7]}; \
    ppkA[4] = f16x2{(f16)pfinA[8],  (f16)pfinA[9]}; \
    ppkA[5] = f16x2{(f16)pfinA[10], (f16)pfinA[11]}; \
    ppkA[6] = f16x2{(f16)pfinA[12], (f16)pfinA[13]}; \
    ppkA[7] = f16x2{(f16)pfinA[14], (f16)pfinA[15]}; \
    ppkB[0] = f16x2{(f16)pfinB[0],  (f16)pfinB[1]}; \
    ppkB[1] = f16x2{(f16)pfinB[2],  (f16)pfinB[3]}; \
    ppkB[2] = f16x2{(f16)pfinB[4],  (f16)pfinB[5]}; \
    ppkB[3] = f16x2{(f16)pfinB[6],  (f16)pfinB[7]}; \
    ppkB[4] = f16x2{(f16)pfinB[8],  (f16)pfinB[9]}; \
    ppkB[5] = f16x2{(f16)pfinB[10], (f16)pfinB[11]}; \
    ppkB[6] = f16x2{(f16)pfinB[12], (f16)pfinB[13]}; \
    ppkB[7] = f16x2{(f16)pfinB[14], (f16)pfinB[15]}; }

__global__ __launch_bounds__(64, 1) void pdfa_main(const float* __restrict__ login,
                                                   char* __restrict__ ws) {
    const int lane = threadIdx.x;
    const int br = lane & 31, hi = lane >> 5;
    const int bid = blockIdx.x;
    const int dir = bid >> 6;              // 0 = forward (t 0..255), 1 = backward (t 511..256)
    const int jp  = bid & 63;              // pair index: b-tiles 2jp, 2jp+1
    const int b0A = (2 * jp) << 5;
    const int b0B = (2 * jp + 1) << 5;

    // constant A-operand fragments (transition table), shared by both chains
    const char* tblb = ws + (dir ? WS_BWDT : WS_FWDT);
    f16x8 af[32];
#pragma unroll
    for (int ks = 0; ks < 32; ++ks)
        af[ks] = *(const f16x8*)(tblb + ks * 1024 + lane * 16);

    // init state vector (own half-wave's 16 states as 8 packed regs), same for A/B
    const float* initv = (const float*)(ws + (dir ? WS_SIG : WS_P0));
    f16x2 ppkA[8], ppkB[8];
#pragma unroll
    for (int i = 0; i < 8; ++i) {
        int s0 = 8 * (i >> 1) + 4 * hi + 2 * (i & 1);
        f16x2 v = f16x2{(f16)initv[s0], (f16)initv[s0 + 1]};
        ppkA[i] = v;
        ppkB[i] = v;
    }

    const float* xbaseA = login + (size_t)(b0A + br) * (LT * NC);
    const float* xbaseB = login + (size_t)(b0B + br) * (LT * NC);
    const f32x16 z{};
    f32x16 pfinA{}, pfinB{};
    f16x2 xqA[8], xqB[8];
    f32x4 xaA0, xaA1, xaA2, xaA3, xbA0, xbA1, xbA2, xbA3;
    f32x4 xaB0, xaB1, xaB2, xaB3, xbB0, xbB1, xbB2, xbB3;

#define TT(S) (dir ? (511 - (S)) : (S))
    XLOAD(xbaseA, xaA0, xaA1, xaA2, xaA3, TT(0))
    XLOAD(xbaseB, xaB0, xaB1, xaB2, xaB3, TT(0))
    XLOAD(xbaseA, xbA0, xbA1, xbA2, xbA3, TT(1))
    XLOAD(xbaseB, xbB0, xbB1, xbB2, xbB3, TT(1))

    for (int s = 0; s < 256; s += 2) {
        XCONV(xqA, xaA0, xaA1, xaA2, xaA3)
        XCONV(xqB, xaB0, xaB1, xaB2, xaB3)
        XLOAD(xbaseA, xaA0, xaA1, xaA2, xaA3, TT(s + 2))   // depth-2 prefetch
        XLOAD(xbaseB, xaB0, xaB1, xaB2, xaB3, TT(s + 2))
        STEPBODY2()
        XCONV(xqA, xbA0, xbA1, xbA2, xbA3)
        XCONV(xqB, xbB0, xbB1, xbB2, xbB3)
        XLOAD(xbaseA, xbA0, xbA1, xbA2, xbA3, TT(s + 3))
        XLOAD(xbaseB, xbB0, xbB1, xbB2, xbB3, TT(s + 3))
        STEPBODY2()
    }
#undef TT

    // write fp32 result vectors: f (fwd) or g (bwd), laid out [state][b]
    float* outv = (float*)(ws + (dir ? WS_G : WS_F));
#pragma unroll
    for (int r = 0; r < 16; ++r) {
        int st = (r & 3) + 8 * (r >> 2) + 4 * hi;
        outv[st * NB + b0A + br] = pfinA[r];
    }
#pragma unroll
    for (int r = 0; r < 16; ++r) {
        int st = (r & 3) + 8 * (r >> 2) + 4 * hi;
        outv[st * NB + b0B + br] = pfinB[r];
    }
}

// ---------------- combine: out[b] = log( f.g / 65536 + 1e-20*sum(sigma) ) ------
__global__ __launch_bounds__(256) void pdfa_combine(const char* __restrict__ ws,
                                                    float* __restrict__ out) {
    int b = blockIdx.x * 256 + threadIdx.x;
    const float* f = (const float*)(ws + WS_F);
    const float* g = (const float*)(ws + WS_G);
    float ss = *(const float*)(ws + WS_SUMSIG);
    float dot = 0.f;
#pragma unroll
    for (int s2 = 0; s2 < 32; ++s2)
        dot = fmaf(f[s2 * NB + b], g[s2 * NB + b], dot);
    out[b] = logf(dot * (1.f / 65536.f) + 1e-20f * ss);
}

extern "C" void kernel_launch(void* const* d_in, const int* in_sizes, int n_in,
                              void* d_out, int out_size, void* d_ws, size_t ws_size,
                              hipStream_t stream) {
    const float* login = (const float*)d_in[0];
    const float* ilog  = (const float*)d_in[1];
    const float* tlog  = (const float*)d_in[2];
    const float* alog  = (const float*)d_in[3];
    char* ws = (char*)d_ws;

    pdfa_prep<<<1, 512, 0, stream>>>(tlog, ilog, alog, ws);
    pdfa_main<<<128, 64, 0, stream>>>(login, ws);
    pdfa_combine<<<NB / 256, 256, 0, stream>>>(ws, (float*)d_out);
}

// Round 4
// 197.570 us; speedup vs baseline: 2.1312x; 2.1312x over previous
//
#include <hip/hip_runtime.h>
#include <math.h>

typedef _Float16 f16;
typedef _Float16 f16x2 __attribute__((ext_vector_type(2)));
typedef _Float16 f16x8 __attribute__((ext_vector_type(8)));
typedef float    f32x4 __attribute__((ext_vector_type(4)));
typedef float    f32x16 __attribute__((ext_vector_type(16)));

#define NB 4096
#define LT 512
#define NC 16
#define NS 32

// workspace layout (bytes)
#define WS_P0     0                     // 32 f32, softmax(init)*256
#define WS_SIG    128                   // 32 f32, sigmoid(acc)*256
#define WS_SUMSIG 256                   // 1 f32
#define WS_FWDT   512                   // 16384 f16 = 32768 B
#define WS_BWDT   (512 + 32768)
#define WS_F      (512 + 65536)         // 32*4096 f32
#define WS_G      (WS_F + 32*4096*4)

#if __has_builtin(__builtin_amdgcn_exp2f)
#define EXP2F __builtin_amdgcn_exp2f
#else
#define EXP2F exp2f
#endif

// ---------------- prep: softmaxes + fragment-ordered fp16 transition tables ----
__global__ __launch_bounds__(512) void pdfa_prep(const float* __restrict__ tlogit,
                                                 const float* __restrict__ ilogit,
                                                 const float* __restrict__ alogit,
                                                 char* __restrict__ ws) {
    int tid = threadIdx.x;           // 512 threads = one (p,c) row each
    f16* fwdT = (f16*)(ws + WS_FWDT);
    f16* bwdT = (f16*)(ws + WS_BWDT);
    int p = tid >> 4, c = tid & 15;
    const float* row = tlogit + p * 512 + c * 32;
    float mx = row[0];
    for (int n = 1; n < 32; ++n) mx = fmaxf(mx, row[n]);
    float s = 0.f;
    for (int n = 0; n < 32; ++n) s += expf(row[n] - mx);
    float inv = 1.f / s;
    int g = p >> 3, ht = (p >> 2) & 1, d = p & 3;
    int chalf = c >> 3, j = c & 7;
    for (int n = 0; n < 32; ++n) {
        float tv = expf(row[n] - mx) * inv;
        // fwd table: GEMM D[m=n']=sum_k T[p,c,n']*y[k], A row m = lane&31 = n
        {
            int ks = 8 * g + 2 * d + chalf;
            int l = 32 * ht + n;
            fwdT[ks * 512 + l * 8 + j] = (f16)tv;
        }
        // bwd table: D[m=p]=sum_{(c,n)} T[p,c,n]*x[c]g[n], A row m = p
        {
            int g2 = n >> 3, h2 = (n >> 2) & 1, d2 = n & 3;
            int ks = 8 * g2 + 2 * d2 + chalf;
            int l = 32 * h2 + p;
            bwdT[ks * 512 + l * 8 + j] = (f16)tv;
        }
    }
    if (tid < 32) {
        float m0 = ilogit[0];
        for (int n = 1; n < 32; ++n) m0 = fmaxf(m0, ilogit[n]);
        float s0 = 0.f;
        for (int n = 0; n < 32; ++n) s0 += expf(ilogit[n] - m0);
        ((float*)(ws + WS_P0))[tid]  = 256.f * expf(ilogit[tid] - m0) / s0;
        ((float*)(ws + WS_SIG))[tid] = 256.f / (1.f + expf(-alogit[tid]));
    }
    if (tid == 0) {
        float ss = 0.f;
        for (int n = 0; n < 32; ++n) ss += 1.f / (1.f + expf(-alogit[n]));
        *(float*)(ws + WS_SUMSIG) = ss;
    }
}

// ---------------- main: K-split-4 — 4 waves per chain, one wave per SIMD -------
#define EC(v) ((f16)EXP2F((v) * 1.44269504089f))

#define XLOAD(B0,B1,B2,B3,T) { const f32x4* sp_ = (const f32x4*)(xbase + (size_t)(T) * NC); \
    B0 = sp_[0]; B1 = sp_[1]; B2 = sp_[2]; B3 = sp_[3]; }

#define XCONV(B0,B1,B2,B3) { \
    xq[0] = f16x2{EC(B0[0]), EC(B0[1])}; \
    xq[1] = f16x2{EC(B0[2]), EC(B0[3])}; \
    xq[2] = f16x2{EC(B1[0]), EC(B1[1])}; \
    xq[3] = f16x2{EC(B1[2]), EC(B1[3])}; \
    xq[4] = f16x2{EC(B2[0]), EC(B2[1])}; \
    xq[5] = f16x2{EC(B2[2]), EC(B2[3])}; \
    xq[6] = f16x2{EC(B3[0]), EC(B3[1])}; \
    xq[7] = f16x2{EC(B3[2]), EC(B3[3])}; }

// one K-step of this wave's slice: m in [0,8), global ks = 8*w + m
// p-scalar: state 8w + 4hi + d, d = m>>1;  c-half = m&1
#define KS4(M, ACC, CIN) { \
    enum { m_ = (M), ch_ = ((M)&1)*4, i_ = ((M)>>2)&1, e_ = ((M)>>1)&1 }; \
    f16 pv_ = ppk[i_][e_]; \
    f16x2 pb_ = {pv_, pv_}; \
    f16x2 y0_ = pb_ * xq[ch_+0], y1_ = pb_ * xq[ch_+1], y2_ = pb_ * xq[ch_+2], y3_ = pb_ * xq[ch_+3]; \
    f16x8 bf_ = {y0_[0],y0_[1],y1_[0],y1_[1],y2_[0],y2_[1],y3_[0],y3_[1]}; \
    ACC = __builtin_amdgcn_mfma_f32_32x32x16_f16(af[m_], bf_, CIN, 0, 0, 0); }

// one time-step: 8 MFMA (4 accs), partial->LDS, barrier, read own 4-state slice,
// convert NEXT step's x while the LDS reads are in flight, rebuild ppk.
#define STEP4(BUF, R0,R1,R2,R3, TNEXT) { \
    f32x16 a0_, a1_, a2_, a3_; \
    KS4(0, a0_, z) KS4(1, a1_, z) KS4(2, a2_, z) KS4(3, a3_, z) \
    KS4(4, a0_, a0_) KS4(5, a1_, a1_) KS4(6, a2_, a2_) KS4(7, a3_, a3_) \
    f32x16 t0_ = a0_ + a1_, t1_ = a2_ + a3_; \
    f32x16 pf_ = t0_ + t1_; \
    float* wp_ = &part[BUF][br][32*w + 4*hi]; \
    *(f32x4*)(wp_ + 0)  = f32x4{pf_[0],  pf_[1],  pf_[2],  pf_[3]}; \
    *(f32x4*)(wp_ + 8)  = f32x4{pf_[4],  pf_[5],  pf_[6],  pf_[7]}; \
    *(f32x4*)(wp_ + 16) = f32x4{pf_[8],  pf_[9],  pf_[10], pf_[11]}; \
    *(f32x4*)(wp_ + 24) = f32x4{pf_[12], pf_[13], pf_[14], pf_[15]}; \
    __syncthreads(); \
    const float* rp_ = &part[BUF][br][8*w + 4*hi]; \
    f32x4 q0_ = *(const f32x4*)(rp_ + 0); \
    f32x4 q1_ = *(const f32x4*)(rp_ + 32); \
    f32x4 q2_ = *(const f32x4*)(rp_ + 64); \
    f32x4 q3_ = *(const f32x4*)(rp_ + 96); \
    XCONV(R0, R1, R2, R3) \
    XLOAD(R0, R1, R2, R3, TNEXT) \
    f32x4 pn_ = (q0_ + q1_) + (q2_ + q3_); \
    pn = pn_; \
    ppk[0] = f16x2{(f16)pn_[0], (f16)pn_[1]}; \
    ppk[1] = f16x2{(f16)pn_[2], (f16)pn_[3]}; }

__global__ __launch_bounds__(256, 1) void pdfa_main(const float* __restrict__ login,
                                                    char* __restrict__ ws) {
    __shared__ float part[2][32][140];      // [buf][b-col][4 waves x 32 n, padded]
    const int tid  = threadIdx.x;
    const int w    = tid >> 6;              // wave = K-slice group g
    const int lane = tid & 63;
    const int br   = tid & 31;
    const int hi   = (tid >> 5) & 1;
    const int bid  = blockIdx.x;
    const int dir  = bid & 1;               // 0 = fwd (t 0..255), 1 = bwd (t 511..256)
    const int b0   = (bid >> 1) << 5;

    // this wave's 8 A-fragments (global ks = 8w + m)
    const char* tblb = ws + (dir ? WS_BWDT : WS_FWDT);
    f16x8 af[8];
#pragma unroll
    for (int m = 0; m < 8; ++m)
        af[m] = *(const f16x8*)(tblb + (8 * w + m) * 1024 + lane * 16);

    // own 4-state slice of the init vector: states 8w + 4hi + {0..3}
    const float* initv = (const float*)(ws + (dir ? WS_SIG : WS_P0));
    f16x2 ppk[2];
#pragma unroll
    for (int i = 0; i < 2; ++i) {
        int s0 = 8 * w + 4 * hi + 2 * i;
        ppk[i] = f16x2{(f16)initv[s0], (f16)initv[s0 + 1]};
    }

    const float* xbase = login + (size_t)(b0 + br) * (LT * NC);
    const f32x16 z{};
    f32x4 pn{};
    f16x2 xq[8];
    f32x4 xa0, xa1, xa2, xa3, xb0, xb1, xb2, xb3;

#define TT(S)  (dir ? (511 - (S)) : (S))
#define TTC(S) TT((((S) > 511) ? 511 : (S)))
    XLOAD(xa0, xa1, xa2, xa3, TT(0))
    XLOAD(xb0, xb1, xb2, xb3, TT(1))
    XCONV(xa0, xa1, xa2, xa3)               // xq = x-hat for step 0
    XLOAD(xa0, xa1, xa2, xa3, TT(2))        // A-buffer now prefetches t=2

    for (int s = 0; s < 256; s += 2) {
        STEP4(0, xb0, xb1, xb2, xb3, TTC(s + 3))   // step s:   converts B (t=s+1), reloads B<-t=s+3
        STEP4(1, xa0, xa1, xa2, xa3, TTC(s + 4))   // step s+1: converts A (t=s+2), reloads A<-t=s+4
    }
#undef TT
#undef TTC

    // final p (states 8w+4hi+{0..3}, col br) -> f or g, laid out [state][b]
    float* outv = (float*)(ws + (dir ? WS_G : WS_F));
    const int stb = 8 * w + 4 * hi;
#pragma unroll
    for (int j = 0; j < 4; ++j)
        outv[(size_t)(stb + j) * NB + b0 + br] = pn[j];
}

// ---------------- combine: out[b] = log( f.g / 65536 + 1e-20*sum(sigma) ) ------
__global__ __launch_bounds__(256) void pdfa_combine(const char* __restrict__ ws,
                                                    float* __restrict__ out) {
    int b = blockIdx.x * 256 + threadIdx.x;
    const float* f = (const float*)(ws + WS_F);
    const float* g = (const float*)(ws + WS_G);
    float ss = *(const float*)(ws + WS_SUMSIG);
    float dot = 0.f;
#pragma unroll
    for (int s2 = 0; s2 < 32; ++s2)
        dot = fmaf(f[s2 * NB + b], g[s2 * NB + b], dot);
    out[b] = logf(dot * (1.f / 65536.f) + 1e-20f * ss);
}

extern "C" void kernel_launch(void* const* d_in, const int* in_sizes, int n_in,
                              void* d_out, int out_size, void* d_ws, size_t ws_size,
                              hipStream_t stream) {
    const float* login = (const float*)d_in[0];
    const float* ilog  = (const float*)d_in[1];
    const float* tlog  = (const float*)d_in[2];
    const float* alog  = (const float*)d_in[3];
    char* ws = (char*)d_ws;

    pdfa_prep<<<1, 512, 0, stream>>>(tlog, ilog, alog, ws);
    pdfa_main<<<256, 256, 0, stream>>>(login, ws);
    pdfa_combine<<<NB / 256, 256, 0, stream>>>(ws, (float*)d_out);
}

// Round 5
// 194.730 us; speedup vs baseline: 2.1623x; 1.0146x over previous
//
#include <hip/hip_runtime.h>
#include <math.h>

typedef _Float16 f16;
typedef _Float16 f16x2 __attribute__((ext_vector_type(2)));
typedef _Float16 f16x4 __attribute__((ext_vector_type(4)));
typedef _Float16 f16x8 __attribute__((ext_vector_type(8)));
typedef float    f32x4 __attribute__((ext_vector_type(4)));
typedef float    f32x16 __attribute__((ext_vector_type(16)));

#define NB 4096
#define LT 512
#define NC 16
#define NS 32

// workspace layout (bytes)
#define WS_P0     0                     // 32 f32, softmax(init)*256
#define WS_SIG    128                   // 32 f32, sigmoid(acc)*256
#define WS_SUMSIG 256                   // 1 f32
#define WS_FWDT   512                   // 16384 f16 = 32768 B
#define WS_BWDT   (512 + 32768)
#define WS_F      (512 + 65536)         // 32*4096 f32
#define WS_G      (WS_F + 32*4096*4)

#if __has_builtin(__builtin_amdgcn_exp2f)
#define EXP2F __builtin_amdgcn_exp2f
#else
#define EXP2F exp2f
#endif

// ---------------- prep: softmaxes + per-state fp16 transition slices ----------
// Slice ks (0..31) = one state; its 16 k-rows = the 16 symbols c, row-half = c-half.
// fwd: slice state = source p (broadcast p[p']); A rows m = n'. A[m=n][k=(ht,j)] = T[p=ks][c=8ht+j][n]
// bwd: slice state = dest  n (broadcast g[n]);  A rows m = p.  A[m=p][k=(ht,j)] = T[p][c=8ht+j][n=ks]
__global__ __launch_bounds__(512) void pdfa_prep(const float* __restrict__ tlogit,
                                                 const float* __restrict__ ilogit,
                                                 const float* __restrict__ alogit,
                                                 char* __restrict__ ws) {
    int tid = threadIdx.x;           // 512 threads = one (p,c) row each
    f16* fwdT = (f16*)(ws + WS_FWDT);
    f16* bwdT = (f16*)(ws + WS_BWDT);
    int p = tid >> 4, c = tid & 15;
    const float* row = tlogit + p * 512 + c * 32;
    float mx = row[0];
    for (int n = 1; n < 32; ++n) mx = fmaxf(mx, row[n]);
    float s = 0.f;
    for (int n = 0; n < 32; ++n) s += expf(row[n] - mx);
    float inv = 1.f / s;
    int ht = c >> 3, j = c & 7;
    for (int n = 0; n < 32; ++n) {
        float tv = expf(row[n] - mx) * inv;
        fwdT[p * 512 + (32 * ht + n) * 8 + j] = (f16)tv;   // lane = 32*ht + n
        bwdT[n * 512 + (32 * ht + p) * 8 + j] = (f16)tv;   // lane = 32*ht + p
    }
    if (tid < 32) {
        float m0 = ilogit[0];
        for (int n = 1; n < 32; ++n) m0 = fmaxf(m0, ilogit[n]);
        float s0 = 0.f;
        for (int n = 0; n < 32; ++n) s0 += expf(ilogit[n] - m0);
        ((float*)(ws + WS_P0))[tid]  = 256.f * expf(ilogit[tid] - m0) / s0;
        ((float*)(ws + WS_SIG))[tid] = 256.f / (1.f + expf(-alogit[tid]));
    }
    if (tid == 0) {
        float ss = 0.f;
        for (int n = 0; n < 32; ++n) ss += 1.f / (1.f + expf(-alogit[n]));
        *(float*)(ws + WS_SUMSIG) = ss;
    }
}

// ---------------- main: K-split-4, per-state slices, f16 partial exchange ------
#define EC(v) ((f16)EXP2F((v) * 1.44269504089f))

// each lane loads/converts only its own half-wave's 8 c-values
#define XLOAD(A0,A1,T) { const f32x4* sp_ = (const f32x4*)(xbase + (size_t)(T) * NC); \
    A0 = sp_[0]; A1 = sp_[1]; }

#define XCONV(A0,A1) { \
    xq[0] = f16x2{EC(A0[0]), EC(A0[1])}; \
    xq[1] = f16x2{EC(A0[2]), EC(A0[3])}; \
    xq[2] = f16x2{EC(A1[0]), EC(A1[1])}; \
    xq[3] = f16x2{EC(A1[2]), EC(A1[3])}; }

// one slice: broadcast state scalar pnew[M], 4 pk_mul on own-half x, one MFMA
#define KS(M, ACC, CIN) { \
    f16 pv_ = pnew[M]; \
    f16x2 pb_ = {pv_, pv_}; \
    f16x2 y0_ = pb_ * xq[0], y1_ = pb_ * xq[1], y2_ = pb_ * xq[2], y3_ = pb_ * xq[3]; \
    f16x8 bf_ = {y0_[0],y0_[1],y1_[0],y1_[1],y2_[0],y2_[1],y3_[0],y3_[1]}; \
    ACC = __builtin_amdgcn_mfma_f32_32x32x16_f16(af[M], bf_, CIN, 0, 0, 0); }

// one time-step: 8 MFMA (4 accs), f16 partial -> LDS, barrier, read 4 slices of
// 8 own states, convert NEXT step's x while reads are in flight, pk_add reduce.
#define STEP(P, R0, R1, TNEXT) { \
    f32x16 a0_, a1_, a2_, a3_; \
    KS(0, a0_, z) KS(1, a1_, z) KS(2, a2_, z) KS(3, a3_, z) \
    KS(4, a0_, a0_) KS(5, a1_, a1_) KS(6, a2_, a2_) KS(7, a3_, a3_) \
    f32x16 pf_ = (a0_ + a1_) + (a2_ + a3_); \
    char* wb_ = lds_w + (P) * 10240; \
    *(f16x4*)(wb_ + 8*hi)      = f16x4{(f16)pf_[0],  (f16)pf_[1],  (f16)pf_[2],  (f16)pf_[3]};  \
    *(f16x4*)(wb_ + 16 + 8*hi) = f16x4{(f16)pf_[4],  (f16)pf_[5],  (f16)pf_[6],  (f16)pf_[7]};  \
    *(f16x4*)(wb_ + 32 + 8*hi) = f16x4{(f16)pf_[8],  (f16)pf_[9],  (f16)pf_[10], (f16)pf_[11]}; \
    *(f16x4*)(wb_ + 48 + 8*hi) = f16x4{(f16)pf_[12], (f16)pf_[13], (f16)pf_[14], (f16)pf_[15]}; \
    __syncthreads(); \
    const char* rb_ = lds_r + (P) * 10240; \
    f16x8 q0_ = *(const f16x8*)(rb_); \
    f16x8 q1_ = *(const f16x8*)(rb_ + 2560); \
    f16x8 q2_ = *(const f16x8*)(rb_ + 5120); \
    f16x8 q3_ = *(const f16x8*)(rb_ + 7680); \
    XCONV(R0, R1) \
    XLOAD(R0, R1, TNEXT) \
    pnew = (q0_ + q1_) + (q2_ + q3_); }

__global__ __launch_bounds__(256, 1) void pdfa_main(const float* __restrict__ login,
                                                    char* __restrict__ ws) {
    // partial buffers: [buf 2][wave 4][br 32][row 40 f16 (32 used, pad 8)] = 20 KB
    __shared__ __align__(16) char partb[2][10240];
    const int tid  = threadIdx.x;
    const int w    = tid >> 6;              // wave = state-group (states 8w..8w+7)
    const int lane = tid & 63;
    const int br   = tid & 31;
    const int hi   = (tid >> 5) & 1;
    const int bid  = blockIdx.x;
    const int dir  = bid & 1;               // 0 = fwd (t 0..255), 1 = bwd (t 511..256)
    const int b0   = (bid >> 1) << 5;

    // this wave's 8 A-slices (states 8w+m), 8 x 16B = 32 VGPRs
    const char* tblb = ws + (dir ? WS_BWDT : WS_FWDT);
    f16x8 af[8];
#pragma unroll
    for (int m = 0; m < 8; ++m)
        af[m] = *(const f16x8*)(tblb + (8 * w + m) * 1024 + lane * 16);

    // running state: own 8 states (8w..8w+7) as f16x8 (both halves identical)
    const float* initv = (const float*)(ws + (dir ? WS_SIG : WS_P0));
    f16x8 pnew;
#pragma unroll
    for (int j = 0; j < 8; ++j) pnew[j] = (f16)initv[8 * w + j];

    // raw x: per lane only its half's 8 c-values
    const float* xbase = login + (size_t)(b0 + br) * (LT * NC) + 8 * hi;
    char* lds_w = &partb[0][0] + w * 2560 + br * 80;
    char* lds_r = &partb[0][0] + br * 80 + 16 * w;
    const f32x16 z{};
    f16x2 xq[4];
    f32x4 xa0, xa1, xb0, xb1;

#define TT(S) (dir ? (511 - (S)) : (S))
    XLOAD(xa0, xa1, TT(0))
    XLOAD(xb0, xb1, TT(1))
    XCONV(xa0, xa1)                         // xq = x-hat for step 0
    XLOAD(xa0, xa1, TT(2))                  // A-buffer now prefetches t=2

    for (int s = 0; s < 256; s += 2) {
        STEP(0, xb0, xb1, TT(s + 3))        // step s:   converts B (t=s+1), reloads B<-t=s+3
        STEP(1, xa0, xa1, TT(s + 4))        // step s+1: converts A (t=s+2), reloads A<-t=s+4
    }
#undef TT

    // final p (states 8w..8w+7, col br) -> f or g, laid out [state][b]
    if (hi == 0) {
        float* outv = (float*)(ws + (dir ? WS_G : WS_F));
#pragma unroll
        for (int j = 0; j < 8; ++j)
            outv[(size_t)(8 * w + j) * NB + b0 + br] = (float)pnew[j];
    }
}

// ---------------- combine: out[b] = log( f.g / 65536 + 1e-20*sum(sigma) ) ------
__global__ __launch_bounds__(256) void pdfa_combine(const char* __restrict__ ws,
                                                    float* __restrict__ out) {
    int b = blockIdx.x * 256 + threadIdx.x;
    const float* f = (const float*)(ws + WS_F);
    const float* g = (const float*)(ws + WS_G);
    float ss = *(const float*)(ws + WS_SUMSIG);
    float dot = 0.f;
#pragma unroll
    for (int s2 = 0; s2 < 32; ++s2)
        dot = fmaf(f[s2 * NB + b], g[s2 * NB + b], dot);
    out[b] = logf(dot * (1.f / 65536.f) + 1e-20f * ss);
}

extern "C" void kernel_launch(void* const* d_in, const int* in_sizes, int n_in,
                              void* d_out, int out_size, void* d_ws, size_t ws_size,
                              hipStream_t stream) {
    const float* login = (const float*)d_in[0];
    const float* ilog  = (const float*)d_in[1];
    const float* tlog  = (const float*)d_in[2];
    const float* alog  = (const float*)d_in[3];
    char* ws = (char*)d_ws;

    pdfa_prep<<<1, 512, 0, stream>>>(tlog, ilog, alog, ws);
    pdfa_main<<<256, 256, 0, stream>>>(login, ws);
    pdfa_combine<<<NB / 256, 256, 0, stream>>>(ws, (float*)d_out);
}

// Round 6
// 192.328 us; speedup vs baseline: 2.1893x; 1.0125x over previous
//
#include <hip/hip_runtime.h>
#include <math.h>

typedef _Float16 f16;
typedef _Float16 f16x2 __attribute__((ext_vector_type(2)));
typedef _Float16 f16x4 __attribute__((ext_vector_type(4)));
typedef _Float16 f16x8 __attribute__((ext_vector_type(8)));
typedef float    f32x4 __attribute__((ext_vector_type(4)));
typedef float    f32x16 __attribute__((ext_vector_type(16)));

#define NB 4096
#define LT 512
#define NC 16
#define NS 32

// workspace layout (bytes)
#define WS_P0     0                     // 32 f32, softmax(init)*256
#define WS_SIG    128                   // 32 f32, sigmoid(acc)*256
#define WS_SUMSIG 256                   // 1 f32
#define WS_FWDT   512                   // 16384 f16 = 32768 B
#define WS_BWDT   (512 + 32768)
#define WS_F      (512 + 65536)         // 32*4096 f32
#define WS_G      (WS_F + 32*4096*4)

#if __has_builtin(__builtin_amdgcn_exp2f)
#define EXP2F __builtin_amdgcn_exp2f
#else
#define EXP2F exp2f
#endif

// ---------------- prep: softmaxes + per-state fp16 transition slices ----------
// Slice ks (0..31) = one state; its 16 k-rows = the 16 symbols c, row-half = c-half.
// fwd: slice state = source p (broadcast p[p']); A rows m = n'. A[m=n][k=(ht,j)] = T[p=ks][c=8ht+j][n]
// bwd: slice state = dest  n (broadcast g[n]);  A rows m = p.  A[m=p][k=(ht,j)] = T[p][c=8ht+j][n=ks]
__global__ __launch_bounds__(512) void pdfa_prep(const float* __restrict__ tlogit,
                                                 const float* __restrict__ ilogit,
                                                 const float* __restrict__ alogit,
                                                 char* __restrict__ ws) {
    int tid = threadIdx.x;           // 512 threads = one (p,c) row each
    f16* fwdT = (f16*)(ws + WS_FWDT);
    f16* bwdT = (f16*)(ws + WS_BWDT);
    int p = tid >> 4, c = tid & 15;
    const float* row = tlogit + p * 512 + c * 32;
    float mx = row[0];
    for (int n = 1; n < 32; ++n) mx = fmaxf(mx, row[n]);
    float s = 0.f;
    for (int n = 0; n < 32; ++n) s += expf(row[n] - mx);
    float inv = 1.f / s;
    int ht = c >> 3, j = c & 7;
    for (int n = 0; n < 32; ++n) {
        float tv = expf(row[n] - mx) * inv;
        fwdT[p * 512 + (32 * ht + n) * 8 + j] = (f16)tv;   // lane = 32*ht + n
        bwdT[n * 512 + (32 * ht + p) * 8 + j] = (f16)tv;   // lane = 32*ht + p
    }
    if (tid < 32) {
        float m0 = ilogit[0];
        for (int n = 1; n < 32; ++n) m0 = fmaxf(m0, ilogit[n]);
        float s0 = 0.f;
        for (int n = 0; n < 32; ++n) s0 += expf(ilogit[n] - m0);
        ((float*)(ws + WS_P0))[tid]  = 256.f * expf(ilogit[tid] - m0) / s0;
        ((float*)(ws + WS_SIG))[tid] = 256.f / (1.f + expf(-alogit[tid]));
    }
    if (tid == 0) {
        float ss = 0.f;
        for (int n = 0; n < 32; ++n) ss += 1.f / (1.f + expf(-alogit[n]));
        *(float*)(ws + WS_SUMSIG) = ss;
    }
}

// ---------------- main: 2 chains/block (fwd+bwd of one tile), K-split-4 each --
#define EC(v) ((f16)EXP2F((v) * 1.44269504089f))

// each lane loads/converts only its own half-wave's 8 c-values
#define XLOAD(A0,A1,T) { const f32x4* sp_ = (const f32x4*)(xbase + (size_t)(T) * NC); \
    A0 = sp_[0]; A1 = sp_[1]; }

#define XCONV(A0,A1) { \
    xq[0] = f16x2{EC(A0[0]), EC(A0[1])}; \
    xq[1] = f16x2{EC(A0[2]), EC(A0[3])}; \
    xq[2] = f16x2{EC(A1[0]), EC(A1[1])}; \
    xq[3] = f16x2{EC(A1[2]), EC(A1[3])}; }

// one slice: broadcast state scalar pnew[M], 4 pk_mul on own-half x, one MFMA
#define KS(M, ACC, CIN) { \
    f16 pv_ = pnew[M]; \
    f16x2 pb_ = {pv_, pv_}; \
    f16x2 y0_ = pb_ * xq[0], y1_ = pb_ * xq[1], y2_ = pb_ * xq[2], y3_ = pb_ * xq[3]; \
    f16x8 bf_ = {y0_[0],y0_[1],y1_[0],y1_[1],y2_[0],y2_[1],y3_[0],y3_[1]}; \
    ACC = __builtin_amdgcn_mfma_f32_32x32x16_f16(af[M], bf_, CIN, 0, 0, 0); }

// one time-step: 8 MFMA (4 accs), f16 partial -> LDS, barrier, read 4 slices of
// 8 own states, convert NEXT step's x while reads are in flight, pk_add reduce.
#define STEP(P, R0, R1, TNEXT) { \
    f32x16 a0_, a1_, a2_, a3_; \
    __builtin_amdgcn_s_setprio(1); \
    KS(0, a0_, z) KS(1, a1_, z) KS(2, a2_, z) KS(3, a3_, z) \
    KS(4, a0_, a0_) KS(5, a1_, a1_) KS(6, a2_, a2_) KS(7, a3_, a3_) \
    __builtin_amdgcn_s_setprio(0); \
    f32x16 pf_ = (a0_ + a1_) + (a2_ + a3_); \
    char* wb_ = lds_w + (P) * 10240; \
    *(f16x4*)(wb_ + 8*hi)      = f16x4{(f16)pf_[0],  (f16)pf_[1],  (f16)pf_[2],  (f16)pf_[3]};  \
    *(f16x4*)(wb_ + 16 + 8*hi) = f16x4{(f16)pf_[4],  (f16)pf_[5],  (f16)pf_[6],  (f16)pf_[7]};  \
    *(f16x4*)(wb_ + 32 + 8*hi) = f16x4{(f16)pf_[8],  (f16)pf_[9],  (f16)pf_[10], (f16)pf_[11]}; \
    *(f16x4*)(wb_ + 48 + 8*hi) = f16x4{(f16)pf_[12], (f16)pf_[13], (f16)pf_[14], (f16)pf_[15]}; \
    __syncthreads(); \
    const char* rb_ = lds_r + (P) * 10240; \
    f16x8 q0_ = *(const f16x8*)(rb_); \
    f16x8 q1_ = *(const f16x8*)(rb_ + 2560); \
    f16x8 q2_ = *(const f16x8*)(rb_ + 5120); \
    f16x8 q3_ = *(const f16x8*)(rb_ + 7680); \
    XCONV(R0, R1) \
    XLOAD(R0, R1, TNEXT) \
    pnew = (q0_ + q1_) + (q2_ + q3_); }

__global__ __launch_bounds__(512, 1) void pdfa_main(const float* __restrict__ login,
                                                    char* __restrict__ ws) {
    // per chain: [buf 2][wave 4][br 32][row 40 f16 (32 used, pad 8)] = 20 KB; 2 chains
    __shared__ __align__(16) char partb[2][2][10240];
    const int tid  = threadIdx.x;
    const int w4   = tid >> 6;              // 0..7
    const int cid  = w4 >> 2;               // chain in block = direction
    const int w    = w4 & 3;                // wave within chain = state-group
    const int lane = tid & 63;
    const int br   = tid & 31;
    const int hi   = (tid >> 5) & 1;
    const int bid  = blockIdx.x;
    const int dir  = cid;                   // 0 = fwd (t 0..255), 1 = bwd (t 511..256)
    const int b0   = bid << 5;

    // this wave's 8 A-slices (states 8w+m), 8 x 16B = 32 VGPRs
    const char* tblb = ws + (dir ? WS_BWDT : WS_FWDT);
    f16x8 af[8];
#pragma unroll
    for (int m = 0; m < 8; ++m)
        af[m] = *(const f16x8*)(tblb + (8 * w + m) * 1024 + lane * 16);

    // running state: own 8 states (8w..8w+7) as f16x8 (both halves identical)
    const float* initv = (const float*)(ws + (dir ? WS_SIG : WS_P0));
    f16x8 pnew;
#pragma unroll
    for (int j = 0; j < 8; ++j) pnew[j] = (f16)initv[8 * w + j];

    // raw x: per lane only its half's 8 c-values
    const float* xbase = login + (size_t)(b0 + br) * (LT * NC) + 8 * hi;
    char* lds_w = &partb[cid][0][0] + w * 2560 + br * 80;
    char* lds_r = &partb[cid][0][0] + br * 80 + 16 * w;
    const f32x16 z{};
    f16x2 xq[4];
    f32x4 xa0, xa1, xb0, xb1;

#define TT(S) (dir ? (511 - (S)) : (S))
    XLOAD(xa0, xa1, TT(0))
    XLOAD(xb0, xb1, TT(1))
    XCONV(xa0, xa1)                         // xq = x-hat for step 0
    XLOAD(xa0, xa1, TT(2))                  // A-buffer now prefetches t=2

    for (int s = 0; s < 256; s += 2) {
        STEP(0, xb0, xb1, TT(s + 3))        // step s:   converts B (t=s+1), reloads B<-t=s+3
        STEP(1, xa0, xa1, TT(s + 4))        // step s+1: converts A (t=s+2), reloads A<-t=s+4
    }
#undef TT

    // final p (states 8w..8w+7, col br) -> f or g, laid out [state][b]
    if (hi == 0) {
        float* outv = (float*)(ws + (dir ? WS_G : WS_F));
#pragma unroll
        for (int j = 0; j < 8; ++j)
            outv[(size_t)(8 * w + j) * NB + b0 + br] = (float)pnew[j];
    }
}

// ---------------- combine: out[b] = log( f.g / 65536 + 1e-20*sum(sigma) ) ------
__global__ __launch_bounds__(256) void pdfa_combine(const char* __restrict__ ws,
                                                    float* __restrict__ out) {
    int b = blockIdx.x * 256 + threadIdx.x;
    const float* f = (const float*)(ws + WS_F);
    const float* g = (const float*)(ws + WS_G);
    float ss = *(const float*)(ws + WS_SUMSIG);
    float dot = 0.f;
#pragma unroll
    for (int s2 = 0; s2 < 32; ++s2)
        dot = fmaf(f[s2 * NB + b], g[s2 * NB + b], dot);
    out[b] = logf(dot * (1.f / 65536.f) + 1e-20f * ss);
}

extern "C" void kernel_launch(void* const* d_in, const int* in_sizes, int n_in,
                              void* d_out, int out_size, void* d_ws, size_t ws_size,
                              hipStream_t stream) {
    const float* login = (const float*)d_in[0];
    const float* ilog  = (const float*)d_in[1];
    const float* tlog  = (const float*)d_in[2];
    const float* alog  = (const float*)d_in[3];
    char* ws = (char*)d_ws;

    pdfa_prep<<<1, 512, 0, stream>>>(tlog, ilog, alog, ws);
    pdfa_main<<<128, 512, 0, stream>>>(login, ws);
    pdfa_combine<<<NB / 256, 256, 0, stream>>>(ws, (float*)d_out);
}

// Round 7
// 151.350 us; speedup vs baseline: 2.7821x; 1.2708x over previous
//
#include <hip/hip_runtime.h>
#include <math.h>

typedef _Float16 f16;
typedef _Float16 f16x2 __attribute__((ext_vector_type(2)));
typedef _Float16 f16x4 __attribute__((ext_vector_type(4)));
typedef _Float16 f16x8 __attribute__((ext_vector_type(8)));
typedef float    f32x4 __attribute__((ext_vector_type(4)));
typedef float    f32x16 __attribute__((ext_vector_type(16)));

#define NB 4096
#define LT 512
#define NC 16
#define NS 32

// workspace layout (bytes)
#define WS_P0     0                     // 32 f32, softmax(init)*256
#define WS_SIG    128                   // 32 f32, sigmoid(acc)*256
#define WS_SUMSIG 256                   // 1 f32
#define WS_FWDT   512                   // 16384 f16 = 32768 B
#define WS_BWDT   (512 + 32768)
#define WS_F      (512 + 65536)         // 32*4096 f32
#define WS_G      (WS_F + 32*4096*4)

#if __has_builtin(__builtin_amdgcn_exp2f)
#define EXP2F __builtin_amdgcn_exp2f
#else
#define EXP2F exp2f
#endif

// ---------------- prep: softmaxes + per-state fp16 transition slices ----------
// Slice ks (0..31) = one state; its 16 k-rows = the 16 symbols c, row-half = c-half.
// fwd: slice state = source p (broadcast p[p']); A rows m = n'. A[m=n][k=(ht,j)] = T[p=ks][c=8ht+j][n]
// bwd: slice state = dest  n (broadcast g[n]);  A rows m = p.  A[m=p][k=(ht,j)] = T[p][c=8ht+j][n=ks]
__global__ __launch_bounds__(512) void pdfa_prep(const float* __restrict__ tlogit,
                                                 const float* __restrict__ ilogit,
                                                 const float* __restrict__ alogit,
                                                 char* __restrict__ ws) {
    int tid = threadIdx.x;           // 512 threads = one (p,c) row each
    f16* fwdT = (f16*)(ws + WS_FWDT);
    f16* bwdT = (f16*)(ws + WS_BWDT);
    int p = tid >> 4, c = tid & 15;
    const float* row = tlogit + p * 512 + c * 32;
    float mx = row[0];
    for (int n = 1; n < 32; ++n) mx = fmaxf(mx, row[n]);
    float s = 0.f;
    for (int n = 0; n < 32; ++n) s += expf(row[n] - mx);
    float inv = 1.f / s;
    int ht = c >> 3, j = c & 7;
    for (int n = 0; n < 32; ++n) {
        float tv = expf(row[n] - mx) * inv;
        fwdT[p * 512 + (32 * ht + n) * 8 + j] = (f16)tv;   // lane = 32*ht + n
        bwdT[n * 512 + (32 * ht + p) * 8 + j] = (f16)tv;   // lane = 32*ht + p
    }
    if (tid < 32) {
        float m0 = ilogit[0];
        for (int n = 1; n < 32; ++n) m0 = fmaxf(m0, ilogit[n]);
        float s0 = 0.f;
        for (int n = 0; n < 32; ++n) s0 += expf(ilogit[n] - m0);
        ((float*)(ws + WS_P0))[tid]  = 256.f * expf(ilogit[tid] - m0) / s0;
        ((float*)(ws + WS_SIG))[tid] = 256.f / (1.f + expf(-alogit[tid]));
    }
    if (tid == 0) {
        float ss = 0.f;
        for (int n = 0; n < 32; ++n) ss += 1.f / (1.f + expf(-alogit[n]));
        *(float*)(ws + WS_SUMSIG) = ss;
    }
}

// ---------------- main: K-split-8 — 1 chain/block, 8 waves, 256 blocks --------
#define EC(v) ((f16)EXP2F((v) * 1.44269504089f))

// each lane loads/converts only its own half-wave's 8 c-values
#define XLOAD(A0,A1,T) { const f32x4* sp_ = (const f32x4*)(xbase + (size_t)(T) * NC); \
    A0 = sp_[0]; A1 = sp_[1]; }

#define XCONV(A0,A1) { \
    xq[0] = f16x2{EC(A0[0]), EC(A0[1])}; \
    xq[1] = f16x2{EC(A0[2]), EC(A0[3])}; \
    xq[2] = f16x2{EC(A1[0]), EC(A1[1])}; \
    xq[3] = f16x2{EC(A1[2]), EC(A1[3])}; }

// one slice: broadcast state scalar pnew[M], 4 pk_mul on own-half x, one MFMA
#define KS(M, ACC, CIN) { \
    f16 pv_ = pnew[M]; \
    f16x2 pb_ = {pv_, pv_}; \
    f16x2 y0_ = pb_ * xq[0], y1_ = pb_ * xq[1], y2_ = pb_ * xq[2], y3_ = pb_ * xq[3]; \
    f16x8 bf_ = {y0_[0],y0_[1],y1_[0],y1_[1],y2_[0],y2_[1],y3_[0],y3_[1]}; \
    ACC = __builtin_amdgcn_mfma_f32_32x32x16_f16(af[M], bf_, CIN, 0, 0, 0); }

// one time-step: 4 MFMA (2 accs), f16 partial -> LDS, barrier, read 8 partials
// of own 4 states, convert NEXT step's x while reads are in flight, pk_add tree.
// LDS row = 72 B (36 f16, 32 used): 18 banks/row, gcd(18,32)=2 -> ~2-way only.
#define STEP(P, R0, R1, TNEXT) { \
    f32x16 a0_, a1_; \
    __builtin_amdgcn_s_setprio(1); \
    KS(0, a0_, z) KS(1, a1_, z) \
    KS(2, a0_, a0_) KS(3, a1_, a1_) \
    __builtin_amdgcn_s_setprio(0); \
    f32x16 pf_ = a0_ + a1_; \
    char* wb_ = lds_w + (P) * 18432; \
    *(f16x4*)(wb_ + 0  + 8*hi) = f16x4{(f16)pf_[0],  (f16)pf_[1],  (f16)pf_[2],  (f16)pf_[3]};  \
    *(f16x4*)(wb_ + 16 + 8*hi) = f16x4{(f16)pf_[4],  (f16)pf_[5],  (f16)pf_[6],  (f16)pf_[7]};  \
    *(f16x4*)(wb_ + 32 + 8*hi) = f16x4{(f16)pf_[8],  (f16)pf_[9],  (f16)pf_[10], (f16)pf_[11]}; \
    *(f16x4*)(wb_ + 48 + 8*hi) = f16x4{(f16)pf_[12], (f16)pf_[13], (f16)pf_[14], (f16)pf_[15]}; \
    __syncthreads(); \
    const char* rb_ = lds_r + (P) * 18432; \
    f16x4 q0_ = *(const f16x4*)(rb_); \
    f16x4 q1_ = *(const f16x4*)(rb_ + 1 * 2304); \
    f16x4 q2_ = *(const f16x4*)(rb_ + 2 * 2304); \
    f16x4 q3_ = *(const f16x4*)(rb_ + 3 * 2304); \
    f16x4 q4_ = *(const f16x4*)(rb_ + 4 * 2304); \
    f16x4 q5_ = *(const f16x4*)(rb_ + 5 * 2304); \
    f16x4 q6_ = *(const f16x4*)(rb_ + 6 * 2304); \
    f16x4 q7_ = *(const f16x4*)(rb_ + 7 * 2304); \
    XCONV(R0, R1) \
    XLOAD(R0, R1, TNEXT) \
    pnew = ((q0_ + q1_) + (q2_ + q3_)) + ((q4_ + q5_) + (q6_ + q7_)); }

__global__ __launch_bounds__(512, 1) void pdfa_main(const float* __restrict__ login,
                                                    char* __restrict__ ws) {
    // [buf 2][wave 8][br 32][row 72 B] = 2 x 18432 = 36 KB
    __shared__ __align__(16) char partb[2][18432];
    const int tid  = threadIdx.x;
    const int w    = tid >> 6;              // 0..7: wave = state-group (states 4w..4w+3)
    const int lane = tid & 63;
    const int br   = tid & 31;
    const int hi   = (tid >> 5) & 1;
    const int bid  = blockIdx.x;
    const int dir  = bid & 1;               // 0 = fwd (t 0..255), 1 = bwd (t 511..256)
    const int b0   = (bid >> 1) << 5;

    // this wave's 4 A-slices (states 4w+m), 4 x 16B = 16 VGPRs
    const char* tblb = ws + (dir ? WS_BWDT : WS_FWDT);
    f16x8 af[4];
#pragma unroll
    for (int m = 0; m < 4; ++m)
        af[m] = *(const f16x8*)(tblb + (4 * w + m) * 1024 + lane * 16);

    // running state: own 4 states (4w..4w+3)
    const float* initv = (const float*)(ws + (dir ? WS_SIG : WS_P0));
    f16x4 pnew;
#pragma unroll
    for (int j = 0; j < 4; ++j) pnew[j] = (f16)initv[4 * w + j];

    // raw x: per lane only its half's 8 c-values
    const float* xbase = login + (size_t)(b0 + br) * (LT * NC) + 8 * hi;
    char* lds_w = &partb[0][0] + w * 2304 + br * 72;
    const char* lds_r = &partb[0][0] + br * 72 + 8 * w;
    const f32x16 z{};
    f16x2 xq[4];
    f32x4 xa0, xa1, xb0, xb1;

#define TT(S) (dir ? (511 - (S)) : (S))
    XLOAD(xa0, xa1, TT(0))
    XLOAD(xb0, xb1, TT(1))
    XCONV(xa0, xa1)                         // xq = x-hat for step 0
    XLOAD(xa0, xa1, TT(2))                  // A-buffer now prefetches t=2

    for (int s = 0; s < 256; s += 2) {
        STEP(0, xb0, xb1, TT(s + 3))        // step s:   converts B (t=s+1), reloads B<-t=s+3
        STEP(1, xa0, xa1, TT(s + 4))        // step s+1: converts A (t=s+2), reloads A<-t=s+4
    }
#undef TT

    // final p (states 4w..4w+3, col br) -> f or g, laid out [state][b]
    if (hi == 0) {
        float* outv = (float*)(ws + (dir ? WS_G : WS_F));
#pragma unroll
        for (int j = 0; j < 4; ++j)
            outv[(size_t)(4 * w + j) * NB + b0 + br] = (float)pnew[j];
    }
}

// ---------------- combine: out[b] = log( f.g / 65536 + 1e-20*sum(sigma) ) ------
__global__ __launch_bounds__(256) void pdfa_combine(const char* __restrict__ ws,
                                                    float* __restrict__ out) {
    int b = blockIdx.x * 256 + threadIdx.x;
    const float* f = (const float*)(ws + WS_F);
    const float* g = (const float*)(ws + WS_G);
    float ss = *(const float*)(ws + WS_SUMSIG);
    float dot = 0.f;
#pragma unroll
    for (int s2 = 0; s2 < 32; ++s2)
        dot = fmaf(f[s2 * NB + b], g[s2 * NB + b], dot);
    out[b] = logf(dot * (1.f / 65536.f) + 1e-20f * ss);
}

extern "C" void kernel_launch(void* const* d_in, const int* in_sizes, int n_in,
                              void* d_out, int out_size, void* d_ws, size_t ws_size,
                              hipStream_t stream) {
    const float* login = (const float*)d_in[0];
    const float* ilog  = (const float*)d_in[1];
    const float* tlog  = (const float*)d_in[2];
    const float* alog  = (const float*)d_in[3];
    char* ws = (char*)d_ws;

    pdfa_prep<<<1, 512, 0, stream>>>(tlog, ilog, alog, ws);
    pdfa_main<<<256, 512, 0, stream>>>(login, ws);
    pdfa_combine<<<NB / 256, 256, 0, stream>>>(ws, (float*)d_out);
}